// Round 2
// baseline (942.736 us; speedup 1.0000x reference)
//
#include <hip/hip_runtime.h>
#include <stdint.h>

#define TPB 256
#define NUM_XCD 8

// --- Fast path ------------------------------------------------------------
// Per-XCD partial buffers in d_ws (NUM_XCD * N floats, pre-zeroed).
// Atomic adds are L2-local (global_atomic_add_f32 with NO sc bits): each
// buffer is touched only by waves on its own physical XCD (HW_REG_XCC_ID),
// so per-XCD L2 non-coherence cannot lose updates. Kernel-end L2 writeback
// publishes the partials to the reduce kernel.

__global__ __launch_bounds__(TPB) void edge_kernel_xcd(
    const float* __restrict__ edge_length,
    const int*   __restrict__ edge_center,
    const int*   __restrict__ edge_neighbor,
    const int*   __restrict__ species,
    const float* __restrict__ scales,
    float* __restrict__ part,   // NUM_XCD * N floats, zeroed before launch
    int E, int N, int T)
{
    int i = blockIdx.x * TPB + threadIdx.x;
    if (i >= E) return;

    uint32_t xcd;
    asm("s_getreg_b32 %0, hwreg(HW_REG_XCC_ID)" : "=s"(xcd));
    xcd &= (NUM_XCD - 1);

    float r = edge_length[i];
    int   c = edge_center[i];
    int   n = edge_neighbor[i];

    float x = r * (1.0f / 6.0f);
    if (x < 1.0f) {
        float l0 = scales[species[c] * T + species[n]];

        // cutoff = 1 - 28 x^6 + 48 x^7 - 21 x^8  (p=6)
        float x2 = x * x;
        float x3 = x2 * x;
        float x6 = x3 * x3;
        float cut = fmaf(x6, fmaf(x, fmaf(x, -21.0f, 48.0f), -28.0f), 1.0f);

        // (r/l0)^(-12)/24 * l0 = (l0/r)^12 * l0 / 24
        float inv   = l0 / r;
        float inv2  = inv * inv;
        float inv4  = inv2 * inv2;
        float inv12 = inv4 * inv4 * inv4;
        float e = inv12 * l0 * (1.0f / 24.0f) * cut;

        float* p = part + (size_t)xcd * (size_t)N + (size_t)c;
        // L2-local fp32 atomic RMW: no sc0 (no return), no sc1 (stays in
        // this XCD's L2 — the only XCD that ever touches this buffer).
        asm volatile("global_atomic_add_f32 %0, %1, off" :: "v"(p), "v"(e) : "memory");
    }
}

__global__ __launch_bounds__(TPB) void reduce_kernel(
    const float* __restrict__ part,
    const float* __restrict__ pae,
    float* __restrict__ out, int N)
{
    int i = blockIdx.x * TPB + threadIdx.x;
    if (i >= N) return;
    float s = pae[i];
#pragma unroll
    for (int x = 0; x < NUM_XCD; ++x)
        s += part[(size_t)x * (size_t)N + i];
    out[i] = s;
}

// --- Fallback path (ws too small): round-1 device-scope atomics -----------

__global__ __launch_bounds__(TPB) void init_out_kernel(
    const float* __restrict__ pae, float* __restrict__ out, int N)
{
    int i = blockIdx.x * TPB + threadIdx.x;
    if (i < N) out[i] = pae[i];
}

__global__ __launch_bounds__(TPB) void edge_kernel_dev(
    const float* __restrict__ edge_length,
    const int*   __restrict__ edge_center,
    const int*   __restrict__ edge_neighbor,
    const int*   __restrict__ species,
    const float* __restrict__ scales,
    float* __restrict__ out,
    int E, int T)
{
    int i = blockIdx.x * TPB + threadIdx.x;
    if (i >= E) return;
    float r = edge_length[i];
    int   c = edge_center[i];
    int   n = edge_neighbor[i];
    float x = r * (1.0f / 6.0f);
    if (x < 1.0f) {
        float l0 = scales[species[c] * T + species[n]];
        float x2 = x * x, x3 = x2 * x, x6 = x3 * x3;
        float cut = fmaf(x6, fmaf(x, fmaf(x, -21.0f, 48.0f), -28.0f), 1.0f);
        float inv = l0 / r;
        float inv2 = inv * inv, inv4 = inv2 * inv2, inv12 = inv4 * inv4 * inv4;
        atomicAdd(&out[c], inv12 * l0 * (1.0f / 24.0f) * cut);
    }
}

extern "C" void kernel_launch(void* const* d_in, const int* in_sizes, int n_in,
                              void* d_out, int out_size, void* d_ws, size_t ws_size,
                              hipStream_t stream) {
    const float* edge_length = (const float*)d_in[0];
    const int*   edge_index  = (const int*)  d_in[1];  // (2,E): [0:E) center, [E:2E) neighbor
    const int*   species     = (const int*)  d_in[2];  // (N,1)
    const float* pae         = (const float*)d_in[3];  // (N,1)
    const float* scales      = (const float*)d_in[4];  // (T,T)
    float*       out         = (float*)d_out;

    const int E = in_sizes[0];
    const int N = in_sizes[3];
    int T = 1;
    while (T * T < in_sizes[4]) ++T;   // T = 5

    const size_t need = (size_t)NUM_XCD * (size_t)N * sizeof(float);

    if (ws_size >= need) {
        float* part = (float*)d_ws;
        hipMemsetAsync(part, 0, need, stream);
        edge_kernel_xcd<<<(E + TPB - 1) / TPB, TPB, 0, stream>>>(
            edge_length, edge_index, edge_index + E, species, scales,
            part, E, N, T);
        reduce_kernel<<<(N + TPB - 1) / TPB, TPB, 0, stream>>>(part, pae, out, N);
    } else {
        init_out_kernel<<<(N + TPB - 1) / TPB, TPB, 0, stream>>>(pae, out, N);
        edge_kernel_dev<<<(E + TPB - 1) / TPB, TPB, 0, stream>>>(
            edge_length, edge_index, edge_index + E, species, scales, out, E, T);
    }
}

// Round 3
// 592.457 us; speedup vs baseline: 1.5912x; 1.5912x over previous
//
#include <hip/hip_runtime.h>
#include <stdint.h>

#define TPB   256
#define EPT   8
#define EPB   (TPB*EPT)     // 2048 edges per scatter block
#define ABITS 14
#define APB   (1<<ABITS)    // 16384 atoms per bucket (64 KB LDS accumulator)
#define MAXB  32            // max bucket count supported by fast path
#define SLICES 16           // parallel slices per bucket in k_accum

// edge energy: (r/l0)^-12 / 24 * l0 * poly_cutoff(r), p=6, r_max=6
__device__ __forceinline__ float edge_energy(float r, float l0) {
    float x = r * (1.0f / 6.0f);
    if (x >= 1.0f) return 0.0f;
    float x2 = x * x, x3 = x2 * x, x6 = x3 * x3;
    float cut = fmaf(x6, fmaf(x, fmaf(x, -21.0f, 48.0f), -28.0f), 1.0f);
    float inv = l0 / r;
    float inv2 = inv * inv, inv4 = inv2 * inv2;
    return inv4 * inv4 * inv4 * l0 * (1.0f / 24.0f) * cut;
}

// ---- K0: per-block bucket histogram (bucket-major counts[b*nb1 + blk]) ----
__global__ __launch_bounds__(TPB) void k_count(
    const int* __restrict__ ec, uint32_t* __restrict__ counts,
    int E, int nb1, int nb)
{
    __shared__ uint32_t hist[MAXB];
    int blk = blockIdx.x;
    for (int t = threadIdx.x; t < MAXB; t += TPB) hist[t] = 0;
    __syncthreads();
    int base = blk * EPB;
#pragma unroll
    for (int j = 0; j < EPT; ++j) {
        int i = base + j * TPB + threadIdx.x;
        if (i < E) atomicAdd(&hist[(uint32_t)ec[i] >> ABITS], 1u);
    }
    __syncthreads();
    for (int t = threadIdx.x; t < nb; t += TPB)
        counts[(size_t)t * nb1 + blk] = hist[t];
}

// ---- K1: exclusive scan down each bucket column; emit column totals ------
__global__ __launch_bounds__(TPB) void k_colscan(
    uint32_t* __restrict__ counts, uint32_t* __restrict__ col_total, int nb1)
{
    __shared__ uint32_t s[TPB];
    int b = blockIdx.x;
    uint32_t carry = 0;
    for (int start = 0; start < nb1; start += TPB) {
        int idx = start + threadIdx.x;
        uint32_t v = (idx < nb1) ? counts[(size_t)b * nb1 + idx] : 0;
        s[threadIdx.x] = v;
        __syncthreads();
        for (int o = 1; o < TPB; o <<= 1) {
            uint32_t add = (threadIdx.x >= o) ? s[threadIdx.x - o] : 0;
            __syncthreads();
            s[threadIdx.x] += add;
            __syncthreads();
        }
        uint32_t incl = s[threadIdx.x];
        uint32_t tot  = s[TPB - 1];
        if (idx < nb1) counts[(size_t)b * nb1 + idx] = incl - v + carry;
        carry += tot;
        __syncthreads();
    }
    if (threadIdx.x == 0) col_total[b] = carry;
}

// ---- K2: exclusive scan of bucket totals -> bucket_off -------------------
__global__ __launch_bounds__(TPB) void k_bucketoff(
    const uint32_t* __restrict__ col_total, uint32_t* __restrict__ bucket_off,
    int nb)
{
    int t = threadIdx.x;
    if (t < nb) {
        uint32_t s = 0;
        for (int k = 0; k < t; ++k) s += col_total[k];
        bucket_off[t] = s;
    }
}

// ---- K3: compute energy + counting-sort block's edges into bucketed[] ----
__global__ __launch_bounds__(TPB) void k_scatter(
    const float* __restrict__ el, const int* __restrict__ ec,
    const int* __restrict__ en, const int* __restrict__ species,
    const float* __restrict__ scales, const uint32_t* __restrict__ counts,
    const uint32_t* __restrict__ bucket_off, uint64_t* __restrict__ bucketed,
    int E, int nb1, int nb, int T)
{
    __shared__ uint32_t cs[EPB];
    __shared__ uint32_t es[EPB];
    __shared__ uint32_t hist[MAXB], lstart[MAXB], lcur[MAXB], gbase[MAXB];
    int blk = blockIdx.x;
    for (int t = threadIdx.x; t < MAXB; t += TPB) hist[t] = 0;
    __syncthreads();

    int base = blk * EPB;
    uint32_t myc[EPT]; float mye[EPT]; int myb[EPT];
#pragma unroll
    for (int j = 0; j < EPT; ++j) {
        int i = base + j * TPB + threadIdx.x;
        if (i < E) {
            float r = el[i];
            uint32_t c = (uint32_t)ec[i];
            int n = en[i];
            float l0 = scales[species[c] * T + species[n]];
            myc[j] = c;
            mye[j] = edge_energy(r, l0);
            myb[j] = (int)(c >> ABITS);
            atomicAdd(&hist[myb[j]], 1u);
        } else {
            myb[j] = -1;
        }
    }
    __syncthreads();

    if (threadIdx.x < nb) {
        uint32_t s = 0;
        for (int k = 0; k < threadIdx.x; ++k) s += hist[k];
        lstart[threadIdx.x] = s;
        lcur[threadIdx.x]   = s;
        gbase[threadIdx.x]  = bucket_off[threadIdx.x]
                            + counts[(size_t)threadIdx.x * nb1 + blk];
    }
    __syncthreads();

#pragma unroll
    for (int j = 0; j < EPT; ++j) {
        if (myb[j] >= 0) {
            uint32_t r = atomicAdd(&lcur[myb[j]], 1u);
            cs[r] = myc[j];
            es[r] = __float_as_uint(mye[j]);
        }
    }
    __syncthreads();

    int cnt = min(EPB, E - base);
    for (int k = threadIdx.x; k < cnt; k += TPB) {
        uint32_t c = cs[k];
        int b = (int)(c >> ABITS);
        uint32_t pos = gbase[b] + ((uint32_t)k - lstart[b]);
        bucketed[pos] = ((uint64_t)c << 32) | (uint64_t)es[k];
    }
}

// ---- K4: per-bucket-slice LDS accumulation -> dense partial --------------
__global__ __launch_bounds__(TPB) void k_accum(
    const uint64_t* __restrict__ bucketed, const uint32_t* __restrict__ bucket_off,
    const uint32_t* __restrict__ col_total, float* __restrict__ partial)
{
    __shared__ float acc[APB];   // 64 KB
    int b = blockIdx.x / SLICES;
    int j = blockIdx.x % SLICES;
    for (int t = threadIdx.x; t < APB; t += TPB) acc[t] = 0.0f;
    __syncthreads();

    uint32_t start = bucket_off[b];
    uint32_t size  = col_total[b];
    uint32_t chunk = (size + SLICES - 1) / SLICES;
    uint32_t s0 = start + (uint32_t)j * chunk;
    uint32_t s1 = start + size;
    if (s0 + chunk < s1) s1 = s0 + chunk;

    for (uint32_t k = s0 + threadIdx.x; k < s1; k += TPB) {
        uint64_t rec = bucketed[k];
        uint32_t c = (uint32_t)(rec >> 32);
        float e = __uint_as_float((uint32_t)rec);
        atomicAdd(&acc[c & (APB - 1)], e);   // ds_add_f32, LDS-local
    }
    __syncthreads();

    float* dst = partial + ((size_t)b * SLICES + j) * APB;
    for (int t = threadIdx.x; t < APB; t += TPB) dst[t] = acc[t];
}

// ---- K5: out = pae + sum over slices ------------------------------------
__global__ __launch_bounds__(TPB) void k_final(
    const float* __restrict__ partial, const float* __restrict__ pae,
    float* __restrict__ out, int N)
{
    int i = blockIdx.x * TPB + threadIdx.x;
    if (i >= N) return;
    int b = i >> ABITS;
    int l = i & (APB - 1);
    const float* p = partial + (size_t)b * SLICES * APB + l;
    float s = pae[i];
#pragma unroll
    for (int j = 0; j < SLICES; ++j) s += p[(size_t)j * APB];
    out[i] = s;
}

// ---- Fallback path (ws too small): device-scope atomics (R1, 942 µs) -----
__global__ __launch_bounds__(TPB) void init_out_kernel(
    const float* __restrict__ pae, float* __restrict__ out, int N)
{
    int i = blockIdx.x * TPB + threadIdx.x;
    if (i < N) out[i] = pae[i];
}

__global__ __launch_bounds__(TPB) void edge_kernel_dev(
    const float* __restrict__ el, const int* __restrict__ ec,
    const int* __restrict__ en, const int* __restrict__ species,
    const float* __restrict__ scales, float* __restrict__ out, int E, int T)
{
    int i = blockIdx.x * TPB + threadIdx.x;
    if (i >= E) return;
    float r = el[i];
    int c = ec[i], n = en[i];
    float l0 = scales[species[c] * T + species[n]];
    float e = edge_energy(r, l0);
    if (e != 0.0f) atomicAdd(&out[c], e);
}

extern "C" void kernel_launch(void* const* d_in, const int* in_sizes, int n_in,
                              void* d_out, int out_size, void* d_ws, size_t ws_size,
                              hipStream_t stream) {
    const float* el      = (const float*)d_in[0];
    const int*   eidx    = (const int*)  d_in[1];   // (2,E): [0:E) center, [E:2E) neighbor
    const int*   species = (const int*)  d_in[2];
    const float* pae     = (const float*)d_in[3];
    const float* scales  = (const float*)d_in[4];
    float*       out     = (float*)d_out;

    const int E = in_sizes[0];
    const int N = in_sizes[3];
    int T = 1;
    while (T * T < in_sizes[4]) ++T;   // T = 5

    const int nb  = (N + APB - 1) / APB;        // 31 buckets
    const int nb1 = (E + EPB - 1) / EPB;        // 7813 scatter blocks

    // ws layout (16B-aligned chunks)
    size_t off = 0;
    auto take = [&](size_t bytes) { size_t o = off; off += (bytes + 15) & ~(size_t)15; return o; };
    size_t o_bucketed = take((size_t)E * 8);
    size_t o_counts   = take((size_t)nb * nb1 * 4);
    size_t o_total    = take((size_t)MAXB * 4);
    size_t o_boff     = take((size_t)MAXB * 4);
    size_t o_partial  = take((size_t)nb * SLICES * APB * 4);
    const size_t need = off;

    if (nb <= MAXB && ws_size >= need) {
        char* ws = (char*)d_ws;
        uint64_t* bucketed  = (uint64_t*)(ws + o_bucketed);
        uint32_t* counts    = (uint32_t*)(ws + o_counts);
        uint32_t* col_total = (uint32_t*)(ws + o_total);
        uint32_t* boff      = (uint32_t*)(ws + o_boff);
        float*    partial   = (float*)   (ws + o_partial);

        k_count<<<nb1, TPB, 0, stream>>>(eidx, counts, E, nb1, nb);
        k_colscan<<<nb, TPB, 0, stream>>>(counts, col_total, nb1);
        k_bucketoff<<<1, TPB, 0, stream>>>(col_total, boff, nb);
        k_scatter<<<nb1, TPB, 0, stream>>>(el, eidx, eidx + E, species, scales,
                                           counts, boff, bucketed, E, nb1, nb, T);
        k_accum<<<nb * SLICES, TPB, 0, stream>>>(bucketed, boff, col_total, partial);
        k_final<<<(N + TPB - 1) / TPB, TPB, 0, stream>>>(partial, pae, out, N);
    } else {
        init_out_kernel<<<(N + TPB - 1) / TPB, TPB, 0, stream>>>(pae, out, N);
        edge_kernel_dev<<<(E + TPB - 1) / TPB, TPB, 0, stream>>>(
            el, eidx, eidx + E, species, scales, out, E, T);
    }
}

// Round 5
// 464.666 us; speedup vs baseline: 2.0288x; 1.2750x over previous
//
#include <hip/hip_runtime.h>
#include <stdint.h>

#define TPB    256
#define EPT    8
#define EPB    (TPB*EPT)     // 2048 edges per scatter block
#define ABITS  13
#define APB    (1<<ABITS)    // 8192 atoms per bucket -> 32 KB LDS accumulator
#define MAXB   64            // max buckets supported by fast path
#define SLICES 8             // parallel slices per bucket in k_accum

// edge energy: (r/l0)^-12 / 24 * l0 * poly_cutoff(r), p=6, r_max=6
__device__ __forceinline__ float edge_energy(float r, float l0) {
    float x = r * (1.0f / 6.0f);
    if (x >= 1.0f) return 0.0f;
    float x2 = x * x, x3 = x2 * x, x6 = x3 * x3;
    float cut = fmaf(x6, fmaf(x, fmaf(x, -21.0f, 48.0f), -28.0f), 1.0f);
    float inv = l0 / r;
    float inv2 = inv * inv, inv4 = inv2 * inv2;
    return inv4 * inv4 * inv4 * l0 * (1.0f / 24.0f) * cut;
}

// record: [31:19] local atom idx (13b), [18:0] value = fp32 bits [30:12],
// round-to-nearest at the dropped 12 bits. rel err ~2.4e-4.
// REQUIRES e >= 0: cut() can round to ~-1e-6 near x->1 (R4 NaN bug), so
// clamp here. True negative magnitude is <=1e-14 -- far below threshold.
__device__ __forceinline__ uint32_t pack_rec(uint32_t c, float e) {
    e = fmaxf(e, 0.0f);
    uint32_t vb  = __float_as_uint(e);
    uint32_t v19 = (vb + 0x800u) >> 12;
    if (v19 > 0x7FFFFu) v19 = 0x7FFFFu;
    return ((c & (APB - 1u)) << 19) | v19;
}
__device__ __forceinline__ float unpack_val(uint32_t rec) {
    return __uint_as_float((rec & 0x7FFFFu) << 12);
}

// ---- K1: compute energy, block-local counting sort, atomic slot reservation,
//          coalesced bucketed record write. No counting pre-pass needed. ----
__global__ __launch_bounds__(TPB) void k_scatter(
    const float* __restrict__ el, const int* __restrict__ ec,
    const int* __restrict__ en, const int* __restrict__ species,
    const float* __restrict__ scales, uint32_t* __restrict__ cursors,
    uint32_t* __restrict__ bucketed, float* __restrict__ spill,
    int E, int nb, int T, int cap)
{
    __shared__ uint32_t cs[EPB];      // packed records, sorted by bucket
    __shared__ uint8_t  bs[EPB];      // bucket of each sorted record
    __shared__ uint32_t hist[MAXB], lstart[MAXB], lcur[MAXB], gbase[MAXB];

    for (int t = threadIdx.x; t < MAXB; t += TPB) hist[t] = 0;
    __syncthreads();

    int base = blockIdx.x * EPB;
    int i0   = base + threadIdx.x * EPT;   // 8 consecutive edges per thread
    uint32_t recs[EPT]; int bkt[EPT]; int nval = 0;

    if (i0 + EPT <= E) {
        float4 r0 = *(const float4*)(el + i0);
        float4 r1 = *(const float4*)(el + i0 + 4);
        int4   c0 = *(const int4*)(ec + i0);
        int4   c1 = *(const int4*)(ec + i0 + 4);
        int4   n0 = *(const int4*)(en + i0);
        int4   n1 = *(const int4*)(en + i0 + 4);
        float rr[EPT] = {r0.x,r0.y,r0.z,r0.w, r1.x,r1.y,r1.z,r1.w};
        int   cc[EPT] = {c0.x,c0.y,c0.z,c0.w, c1.x,c1.y,c1.z,c1.w};
        int   nn[EPT] = {n0.x,n0.y,n0.z,n0.w, n1.x,n1.y,n1.z,n1.w};
        nval = EPT;
#pragma unroll
        for (int j = 0; j < EPT; ++j) {
            float l0 = scales[species[cc[j]] * T + species[nn[j]]];
            recs[j]  = pack_rec((uint32_t)cc[j], edge_energy(rr[j], l0));
            bkt[j]   = (int)((uint32_t)cc[j] >> ABITS);
            atomicAdd(&hist[bkt[j]], 1u);
        }
    } else if (i0 < E) {
        for (int j = 0; j < EPT && i0 + j < E; ++j) {
            int i = i0 + j;
            int c = ec[i];
            float l0 = scales[species[c] * T + species[en[i]]];
            recs[nval] = pack_rec((uint32_t)c, edge_energy(el[i], l0));
            bkt[nval]  = (int)((uint32_t)c >> ABITS);
            atomicAdd(&hist[bkt[nval]], 1u);
            ++nval;
        }
    }
    __syncthreads();

    if (threadIdx.x < nb) {
        uint32_t s = 0;
        for (int k = 0; k < threadIdx.x; ++k) s += hist[k];
        lstart[threadIdx.x] = s;
        lcur[threadIdx.x]   = s;
        uint32_t c = hist[threadIdx.x];
        gbase[threadIdx.x]  = c ? atomicAdd(&cursors[threadIdx.x], c) : 0u;
    }
    __syncthreads();

    for (int j = 0; j < nval; ++j) {
        uint32_t r = atomicAdd(&lcur[bkt[j]], 1u);
        cs[r] = recs[j];
        bs[r] = (uint8_t)bkt[j];
    }
    __syncthreads();

    int cnt = min(EPB, E - base);
    for (int k = threadIdx.x; k < cnt; k += TPB) {
        int b = bs[k];
        uint32_t pib = gbase[b] + ((uint32_t)k - lstart[b]);
        if (pib < (uint32_t)cap) {
            bucketed[(size_t)b * (size_t)cap + pib] = cs[k];
        } else {
            // capacity overflow safety net (expected 0 hits): device atomic
            uint32_t rec = cs[k];
            int atom = (b << ABITS) | (int)(rec >> 19);
            atomicAdd(&spill[atom], unpack_val(rec));
        }
    }
}

// ---- K2: per-bucket-slice LDS accumulation -> dense partials -------------
__global__ __launch_bounds__(TPB) void k_accum(
    const uint32_t* __restrict__ bucketed, const uint32_t* __restrict__ cursors,
    float* __restrict__ partial, int cap)
{
    __shared__ float acc[APB];   // 32 KB
    int b = blockIdx.x / SLICES;
    int j = blockIdx.x % SLICES;
    for (int t = threadIdx.x; t < APB; t += TPB) acc[t] = 0.0f;
    __syncthreads();

    uint32_t size = cursors[b];
    if (size > (uint32_t)cap) size = (uint32_t)cap;
    uint32_t chunk = (((size + SLICES - 1) / SLICES) + 3u) & ~3u;
    uint32_t s0 = (uint32_t)j * chunk;
    uint32_t s1 = s0 + chunk; if (s1 > size) s1 = size;
    const uint32_t* src = bucketed + (size_t)b * (size_t)cap;

    for (uint32_t k = s0 + (uint32_t)threadIdx.x * 4u; k < s1; k += TPB * 4u) {
        if (k + 4u <= s1) {
            uint4 r4 = *(const uint4*)(src + k);
            atomicAdd(&acc[r4.x >> 19], unpack_val(r4.x));
            atomicAdd(&acc[r4.y >> 19], unpack_val(r4.y));
            atomicAdd(&acc[r4.z >> 19], unpack_val(r4.z));
            atomicAdd(&acc[r4.w >> 19], unpack_val(r4.w));
        } else {
            for (uint32_t kk = k; kk < s1; ++kk) {
                uint32_t r = src[kk];
                atomicAdd(&acc[r >> 19], unpack_val(r));
            }
        }
    }
    __syncthreads();

    float* dst = partial + ((size_t)b * SLICES + j) * APB;
    for (int t = threadIdx.x; t < APB; t += TPB) dst[t] = acc[t];
}

// ---- K3: out = pae + spill + sum over slices -----------------------------
__global__ __launch_bounds__(TPB) void k_final(
    const float* __restrict__ partial, const float* __restrict__ spill,
    const float* __restrict__ pae, float* __restrict__ out, int N)
{
    int i = blockIdx.x * TPB + threadIdx.x;
    if (i >= N) return;
    int b = i >> ABITS;
    int l = i & (APB - 1);
    const float* p = partial + (size_t)b * SLICES * APB + l;
    float s = pae[i] + spill[i];
#pragma unroll
    for (int j = 0; j < SLICES; ++j) s += p[(size_t)j * APB];
    out[i] = s;
}

// ---- Fallback path (ws too small): device-scope atomics ------------------
__global__ __launch_bounds__(TPB) void init_out_kernel(
    const float* __restrict__ pae, float* __restrict__ out, int N)
{
    int i = blockIdx.x * TPB + threadIdx.x;
    if (i < N) out[i] = pae[i];
}

__global__ __launch_bounds__(TPB) void edge_kernel_dev(
    const float* __restrict__ el, const int* __restrict__ ec,
    const int* __restrict__ en, const int* __restrict__ species,
    const float* __restrict__ scales, float* __restrict__ out, int E, int T)
{
    int i = blockIdx.x * TPB + threadIdx.x;
    if (i >= E) return;
    float r = el[i];
    int c = ec[i], n = en[i];
    float l0 = scales[species[c] * T + species[n]];
    float e = edge_energy(r, l0);
    if (e != 0.0f) atomicAdd(&out[c], e);
}

extern "C" void kernel_launch(void* const* d_in, const int* in_sizes, int n_in,
                              void* d_out, int out_size, void* d_ws, size_t ws_size,
                              hipStream_t stream) {
    const float* el      = (const float*)d_in[0];
    const int*   eidx    = (const int*)  d_in[1];   // (2,E): [0:E) center, [E:2E) neighbor
    const int*   species = (const int*)  d_in[2];
    const float* pae     = (const float*)d_in[3];
    const float* scales  = (const float*)d_in[4];
    float*       out     = (float*)d_out;

    const int E = in_sizes[0];
    const int N = in_sizes[3];
    int T = 1;
    while (T * T < in_sizes[4]) ++T;   // T = 5

    const int nb  = (N + APB - 1) / APB;           // 62 buckets
    const int nb1 = (E + EPB - 1) / EPB;           // 7813 scatter blocks
    // per-bucket capacity: ~1.25x mean, rounded up to 1024 (uint4-aligned)
    const int cap = (int)((((size_t)E / (size_t)nb) * 5 / 4 + 1023) & ~(size_t)1023);

    size_t off = 0;
    auto take = [&](size_t bytes) { size_t o = off; off += (bytes + 15) & ~(size_t)15; return o; };
    size_t o_bucketed = take((size_t)nb * (size_t)cap * 4);
    size_t o_cursors  = take((size_t)MAXB * 4);
    size_t o_spill    = take((size_t)N * 4);
    size_t o_partial  = take((size_t)nb * SLICES * APB * 4);
    const size_t need = off;

    if (nb <= MAXB && ws_size >= need) {
        char* ws = (char*)d_ws;
        uint32_t* bucketed = (uint32_t*)(ws + o_bucketed);
        uint32_t* cursors  = (uint32_t*)(ws + o_cursors);
        float*    spill    = (float*)   (ws + o_spill);
        float*    partial  = (float*)   (ws + o_partial);

        hipMemsetAsync(cursors, 0, (size_t)MAXB * 4, stream);
        hipMemsetAsync(spill,   0, (size_t)N * 4, stream);

        k_scatter<<<nb1, TPB, 0, stream>>>(el, eidx, eidx + E, species, scales,
                                           cursors, bucketed, spill, E, nb, T, cap);
        k_accum<<<nb * SLICES, TPB, 0, stream>>>(bucketed, cursors, partial, cap);
        k_final<<<(N + TPB - 1) / TPB, TPB, 0, stream>>>(partial, spill, pae, out, N);
    } else {
        init_out_kernel<<<(N + TPB - 1) / TPB, TPB, 0, stream>>>(pae, out, N);
        edge_kernel_dev<<<(E + TPB - 1) / TPB, TPB, 0, stream>>>(
            el, eidx, eidx + E, species, scales, out, E, T);
    }
}

// Round 6
// 454.058 us; speedup vs baseline: 2.0762x; 1.0234x over previous
//
#include <hip/hip_runtime.h>
#include <stdint.h>

#define TPB_S  512
#define EPT    8
#define EPB    (TPB_S*EPT)   // 4096 edges per scatter block
#define ABITS  11
#define APB    (1<<ABITS)    // 2048 atoms per bucket -> 8 KB LDS accumulator
#define MAXB   256           // max buckets supported by fast path
#define TPB_A  1024          // accum block threads

// edge energy: (r/l0)^-12 / 24 * l0 * poly_cutoff(r), p=6, r_max=6
__device__ __forceinline__ float edge_energy(float r, float l0) {
    float x = r * (1.0f / 6.0f);
    if (x >= 1.0f) return 0.0f;
    float x2 = x * x, x3 = x2 * x, x6 = x3 * x3;
    float cut = fmaf(x6, fmaf(x, fmaf(x, -21.0f, 48.0f), -28.0f), 1.0f);
    float inv = l0 / r;
    float inv2 = inv * inv, inv4 = inv2 * inv2;
    return inv4 * inv4 * inv4 * l0 * (1.0f / 24.0f) * cut;
}

// record: [29:19] local atom idx (11b), [18:0] value = fp32 bits [30:12],
// round-to-nearest at the dropped 12 bits. rel err ~2.4e-4.
// REQUIRES e >= 0 (cut() can round to ~-1e-6 near x->1): clamp; true negative
// magnitude <=1e-14, far below threshold.
__device__ __forceinline__ uint32_t pack_rec(uint32_t c, float e) {
    e = fmaxf(e, 0.0f);
    uint32_t vb  = __float_as_uint(e);
    uint32_t v19 = (vb + 0x800u) >> 12;
    if (v19 > 0x7FFFFu) v19 = 0x7FFFFu;
    return ((c & (APB - 1u)) << 19) | v19;
}
__device__ __forceinline__ float unpack_val(uint32_t rec) {
    return __uint_as_float((rec & 0x7FFFFu) << 12);
}

// ---- K1: compute energy, block-local counting sort, atomic slot reservation,
//          coalesced bucketed record write. ---------------------------------
__global__ __launch_bounds__(TPB_S) void k_scatter(
    const float* __restrict__ el, const int* __restrict__ ec,
    const int* __restrict__ en, const int* __restrict__ species,
    const float* __restrict__ scales, uint32_t* __restrict__ cursors,
    uint32_t* __restrict__ bucketed, float* __restrict__ spill,
    int E, int nb, int T, int cap)
{
    __shared__ uint32_t cs[EPB];      // packed records, sorted by bucket (16 KB)
    __shared__ uint8_t  bs[EPB];      // bucket of each sorted record (4 KB)
    __shared__ uint32_t hist[MAXB], lstart[MAXB], lcur[MAXB], gbase[MAXB];

    for (int t = threadIdx.x; t < MAXB; t += TPB_S) hist[t] = 0;
    __syncthreads();

    int base = blockIdx.x * EPB;
    int i0   = base + threadIdx.x * EPT;   // 8 consecutive edges per thread
    uint32_t recs[EPT]; int bkt[EPT]; int nval = 0;

    if (i0 + EPT <= E) {
        float4 r0 = *(const float4*)(el + i0);
        float4 r1 = *(const float4*)(el + i0 + 4);
        int4   c0 = *(const int4*)(ec + i0);
        int4   c1 = *(const int4*)(ec + i0 + 4);
        int4   n0 = *(const int4*)(en + i0);
        int4   n1 = *(const int4*)(en + i0 + 4);
        float rr[EPT] = {r0.x,r0.y,r0.z,r0.w, r1.x,r1.y,r1.z,r1.w};
        int   cc[EPT] = {c0.x,c0.y,c0.z,c0.w, c1.x,c1.y,c1.z,c1.w};
        int   nn[EPT] = {n0.x,n0.y,n0.z,n0.w, n1.x,n1.y,n1.z,n1.w};
        nval = EPT;
#pragma unroll
        for (int j = 0; j < EPT; ++j) {
            float l0 = scales[species[cc[j]] * T + species[nn[j]]];
            recs[j]  = pack_rec((uint32_t)cc[j], edge_energy(rr[j], l0));
            bkt[j]   = (int)((uint32_t)cc[j] >> ABITS);
            atomicAdd(&hist[bkt[j]], 1u);
        }
    } else if (i0 < E) {
        for (int j = 0; j < EPT && i0 + j < E; ++j) {
            int i = i0 + j;
            int c = ec[i];
            float l0 = scales[species[c] * T + species[en[i]]];
            recs[nval] = pack_rec((uint32_t)c, edge_energy(el[i], l0));
            bkt[nval]  = (int)((uint32_t)c >> ABITS);
            atomicAdd(&hist[bkt[nval]], 1u);
            ++nval;
        }
    }
    __syncthreads();

    if (threadIdx.x < nb) {
        uint32_t s = 0;
        for (int k = 0; k < threadIdx.x; ++k) s += hist[k];
        lstart[threadIdx.x] = s;
        lcur[threadIdx.x]   = s;
        uint32_t c = hist[threadIdx.x];
        gbase[threadIdx.x]  = c ? atomicAdd(&cursors[threadIdx.x], c) : 0u;
    }
    __syncthreads();

    for (int j = 0; j < nval; ++j) {
        uint32_t r = atomicAdd(&lcur[bkt[j]], 1u);
        cs[r] = recs[j];
        bs[r] = (uint8_t)bkt[j];
    }
    __syncthreads();

    int cnt = min(EPB, E - base);
    for (int k = threadIdx.x; k < cnt; k += TPB_S) {
        int b = bs[k];
        uint32_t pib = gbase[b] + ((uint32_t)k - lstart[b]);
        if (pib < (uint32_t)cap) {
            bucketed[(size_t)b * (size_t)cap + pib] = cs[k];
        } else {
            // capacity overflow safety net (expected ~0 hits): device atomic
            uint32_t rec = cs[k];
            int atom = (b << ABITS) | (int)(rec >> 19);
            atomicAdd(&spill[atom], unpack_val(rec));
        }
    }
}

// ---- K2: one block owns one 2048-atom bucket: LDS-accumulate its records,
//          then write out = pae + spill + acc directly. No partials. --------
__global__ __launch_bounds__(TPB_A) void k_accum_out(
    const uint32_t* __restrict__ bucketed, const uint32_t* __restrict__ cursors,
    const float* __restrict__ spill, const float* __restrict__ pae,
    float* __restrict__ out, int N, int cap)
{
    __shared__ float acc[APB];   // 8 KB
    int b = blockIdx.x;
    for (int t = threadIdx.x; t < APB; t += TPB_A) acc[t] = 0.0f;
    __syncthreads();

    uint32_t size = cursors[b];
    if (size > (uint32_t)cap) size = (uint32_t)cap;
    const uint32_t* src = bucketed + (size_t)b * (size_t)cap;

    for (uint32_t k = (uint32_t)threadIdx.x * 4u; k < size; k += TPB_A * 4u) {
        if (k + 4u <= size) {
            uint4 r4 = *(const uint4*)(src + k);
            atomicAdd(&acc[r4.x >> 19], unpack_val(r4.x));
            atomicAdd(&acc[r4.y >> 19], unpack_val(r4.y));
            atomicAdd(&acc[r4.z >> 19], unpack_val(r4.z));
            atomicAdd(&acc[r4.w >> 19], unpack_val(r4.w));
        } else {
            for (uint32_t kk = k; kk < size; ++kk) {
                uint32_t r = src[kk];
                atomicAdd(&acc[r >> 19], unpack_val(r));
            }
        }
    }
    __syncthreads();

    int g0 = b << ABITS;
    for (int l = threadIdx.x; l < APB; l += TPB_A) {
        int g = g0 + l;
        if (g < N) out[g] = pae[g] + spill[g] + acc[l];
    }
}

// ---- Fallback path (ws too small): device-scope atomics ------------------
__global__ __launch_bounds__(256) void init_out_kernel(
    const float* __restrict__ pae, float* __restrict__ out, int N)
{
    int i = blockIdx.x * 256 + threadIdx.x;
    if (i < N) out[i] = pae[i];
}

__global__ __launch_bounds__(256) void edge_kernel_dev(
    const float* __restrict__ el, const int* __restrict__ ec,
    const int* __restrict__ en, const int* __restrict__ species,
    const float* __restrict__ scales, float* __restrict__ out, int E, int T)
{
    int i = blockIdx.x * 256 + threadIdx.x;
    if (i >= E) return;
    float r = el[i];
    int c = ec[i], n = en[i];
    float l0 = scales[species[c] * T + species[n]];
    float e = edge_energy(r, l0);
    if (e != 0.0f) atomicAdd(&out[c], e);
}

extern "C" void kernel_launch(void* const* d_in, const int* in_sizes, int n_in,
                              void* d_out, int out_size, void* d_ws, size_t ws_size,
                              hipStream_t stream) {
    const float* el      = (const float*)d_in[0];
    const int*   eidx    = (const int*)  d_in[1];   // (2,E): [0:E) center, [E:2E) neighbor
    const int*   species = (const int*)  d_in[2];
    const float* pae     = (const float*)d_in[3];
    const float* scales  = (const float*)d_in[4];
    float*       out     = (float*)d_out;

    const int E = in_sizes[0];
    const int N = in_sizes[3];
    int T = 1;
    while (T * T < in_sizes[4]) ++T;   // T = 5

    const int nb  = (N + APB - 1) / APB;           // 245 buckets
    const int nb1 = (E + EPB - 1) / EPB;           // 3907 scatter blocks
    // per-bucket capacity: ~1.25x mean, rounded up to 1024 (uint4-aligned)
    const int cap = (int)((((size_t)E / (size_t)nb) * 5 / 4 + 1023) & ~(size_t)1023);

    size_t off = 0;
    auto take = [&](size_t bytes) { size_t o = off; off += (bytes + 15) & ~(size_t)15; return o; };
    size_t o_bucketed = take((size_t)nb * (size_t)cap * 4);
    size_t o_cursors  = take((size_t)MAXB * 4);
    size_t o_spill    = take((size_t)N * 4);
    const size_t need = off;

    if (nb <= MAXB && ws_size >= need) {
        char* ws = (char*)d_ws;
        uint32_t* bucketed = (uint32_t*)(ws + o_bucketed);
        uint32_t* cursors  = (uint32_t*)(ws + o_cursors);
        float*    spill    = (float*)   (ws + o_spill);

        hipMemsetAsync(cursors, 0, (size_t)MAXB * 4, stream);
        hipMemsetAsync(spill,   0, (size_t)N * 4, stream);

        k_scatter<<<nb1, TPB_S, 0, stream>>>(el, eidx, eidx + E, species, scales,
                                             cursors, bucketed, spill, E, nb, T, cap);
        k_accum_out<<<nb, TPB_A, 0, stream>>>(bucketed, cursors, spill, pae, out, N, cap);
    } else {
        init_out_kernel<<<(N + 255) / 256, 256, 0, stream>>>(pae, out, N);
        edge_kernel_dev<<<(E + 255) / 256, 256, 0, stream>>>(
            el, eidx, eidx + E, species, scales, out, E, T);
    }
}

// Round 7
// 353.922 us; speedup vs baseline: 2.6637x; 1.2829x over previous
//
#include <hip/hip_runtime.h>
#include <stdint.h>

#define TPB_S  512
#define EPT    8
#define EPB    (TPB_S*EPT)   // 4096 edges per scatter block
#define ABITS  11
#define APB    (1<<ABITS)    // 2048 atoms per bucket -> 8 KB LDS accumulator
#define MAXB   256           // max buckets supported by fast path
#define TPB_A  1024          // accum block threads

// edge energy: (r/l0)^-12 / 24 * l0 * poly_cutoff(r), p=6, r_max=6
__device__ __forceinline__ float edge_energy(float r, float l0) {
    float x = r * (1.0f / 6.0f);
    if (x >= 1.0f) return 0.0f;
    float x2 = x * x, x3 = x2 * x, x6 = x3 * x3;
    float cut = fmaf(x6, fmaf(x, fmaf(x, -21.0f, 48.0f), -28.0f), 1.0f);
    float inv = l0 / r;
    float inv2 = inv * inv, inv4 = inv2 * inv2;
    return inv4 * inv4 * inv4 * l0 * (1.0f / 24.0f) * cut;
}

// record: [29:19] local atom idx (11b), [18:0] value = fp32 bits [30:12],
// round-to-nearest at dropped 12 bits (rel err ~2.4e-4). Requires e>=0:
// cut() can round to ~-1e-6 near x->1 (R4 NaN), so clamp (true neg <=1e-14).
__device__ __forceinline__ uint32_t pack_rec(uint32_t c, float e) {
    e = fmaxf(e, 0.0f);
    uint32_t vb  = __float_as_uint(e);
    uint32_t v19 = (vb + 0x800u) >> 12;
    if (v19 > 0x7FFFFu) v19 = 0x7FFFFu;
    return ((c & (APB - 1u)) << 19) | v19;
}
__device__ __forceinline__ float unpack_val(uint32_t rec) {
    return __uint_as_float((rec & 0x7FFFFu) << 12);
}

// ---- K0: detect uniform scales matrix (1 thread). flag+value -> ws -------
__global__ void k_check(const float* __restrict__ scales, int tt,
                        uint32_t* __restrict__ uflag)
{
    float v0 = scales[0];
    bool same = true;
    for (int k = 1; k < tt; ++k) same &= (__float_as_uint(scales[k]) == __float_as_uint(v0));
    uflag[0] = same ? 1u : 0u;
    uflag[1] = __float_as_uint(v0);
}

// ---- K1: energy + block-local counting sort + atomic slot reservation +
//          coalesced bucketed record write. Uniform-l0 fast path skips the
//          32M species gathers and the whole `en` stream. ------------------
__global__ __launch_bounds__(TPB_S) void k_scatter(
    const float* __restrict__ el, const int* __restrict__ ec,
    const int* __restrict__ en, const int* __restrict__ species,
    const float* __restrict__ scales, const uint32_t* __restrict__ uflag,
    uint32_t* __restrict__ cursors, uint32_t* __restrict__ bucketed,
    float* __restrict__ spill, int E, int nb, int T, int cap)
{
    __shared__ uint32_t cs[EPB];      // packed records, sorted by bucket (16 KB)
    __shared__ uint8_t  bs[EPB];      // bucket of each sorted record (4 KB)
    __shared__ uint32_t hist[MAXB], lstart[MAXB], lcur[MAXB], gbase[MAXB];

    for (int t = threadIdx.x; t < MAXB; t += TPB_S) hist[t] = 0;
    __syncthreads();

    const uint32_t uni = uflag[0];
    const float    ul0 = __uint_as_float(uflag[1]);

    int base = blockIdx.x * EPB;
    int i0   = base + threadIdx.x * EPT;   // 8 consecutive edges per thread
    uint32_t recs[EPT]; int bkt[EPT]; int nval = 0;

    if (i0 + EPT <= E) {
        float4 r0 = *(const float4*)(el + i0);
        float4 r1 = *(const float4*)(el + i0 + 4);
        int4   c0 = *(const int4*)(ec + i0);
        int4   c1 = *(const int4*)(ec + i0 + 4);
        float rr[EPT] = {r0.x,r0.y,r0.z,r0.w, r1.x,r1.y,r1.z,r1.w};
        int   cc[EPT] = {c0.x,c0.y,c0.z,c0.w, c1.x,c1.y,c1.z,c1.w};
        nval = EPT;
        if (uni) {
#pragma unroll
            for (int j = 0; j < EPT; ++j) {
                recs[j] = pack_rec((uint32_t)cc[j], edge_energy(rr[j], ul0));
                bkt[j]  = (int)((uint32_t)cc[j] >> ABITS);
                atomicAdd(&hist[bkt[j]], 1u);
            }
        } else {
            int4 n0 = *(const int4*)(en + i0);
            int4 n1 = *(const int4*)(en + i0 + 4);
            int  nn[EPT] = {n0.x,n0.y,n0.z,n0.w, n1.x,n1.y,n1.z,n1.w};
#pragma unroll
            for (int j = 0; j < EPT; ++j) {
                float l0 = scales[species[cc[j]] * T + species[nn[j]]];
                recs[j] = pack_rec((uint32_t)cc[j], edge_energy(rr[j], l0));
                bkt[j]  = (int)((uint32_t)cc[j] >> ABITS);
                atomicAdd(&hist[bkt[j]], 1u);
            }
        }
    } else if (i0 < E) {
        for (int j = 0; j < EPT && i0 + j < E; ++j) {
            int i = i0 + j;
            int c = ec[i];
            float l0 = uni ? ul0 : scales[species[c] * T + species[en[i]]];
            recs[nval] = pack_rec((uint32_t)c, edge_energy(el[i], l0));
            bkt[nval]  = (int)((uint32_t)c >> ABITS);
            atomicAdd(&hist[bkt[nval]], 1u);
            ++nval;
        }
    }
    __syncthreads();

    if (threadIdx.x < nb) {
        uint32_t s = 0;
        for (int k = 0; k < threadIdx.x; ++k) s += hist[k];
        lstart[threadIdx.x] = s;
        lcur[threadIdx.x]   = s;
        uint32_t c = hist[threadIdx.x];
        gbase[threadIdx.x]  = c ? atomicAdd(&cursors[threadIdx.x], c) : 0u;
    }
    __syncthreads();

    for (int j = 0; j < nval; ++j) {
        uint32_t r = atomicAdd(&lcur[bkt[j]], 1u);
        cs[r] = recs[j];
        bs[r] = (uint8_t)bkt[j];
    }
    __syncthreads();

    int cnt = min(EPB, E - base);
    for (int k = threadIdx.x; k < cnt; k += TPB_S) {
        int b = bs[k];
        uint32_t pib = gbase[b] + ((uint32_t)k - lstart[b]);
        if (pib < (uint32_t)cap) {
            bucketed[(size_t)b * (size_t)cap + pib] = cs[k];
        } else {
            // capacity overflow safety net (expected ~0 hits): device atomic
            uint32_t rec = cs[k];
            int atom = (b << ABITS) | (int)(rec >> 19);
            atomicAdd(&spill[atom], unpack_val(rec));
        }
    }
}

// ---- K2: one block owns one 2048-atom bucket: LDS-accumulate its records,
//          write out = pae + spill + acc directly. -------------------------
__global__ __launch_bounds__(TPB_A) void k_accum_out(
    const uint32_t* __restrict__ bucketed, const uint32_t* __restrict__ cursors,
    const float* __restrict__ spill, const float* __restrict__ pae,
    float* __restrict__ out, int N, int cap)
{
    __shared__ float acc[APB];   // 8 KB
    int b = blockIdx.x;
    for (int t = threadIdx.x; t < APB; t += TPB_A) acc[t] = 0.0f;
    __syncthreads();

    uint32_t size = cursors[b];
    if (size > (uint32_t)cap) size = (uint32_t)cap;
    const uint32_t* src = bucketed + (size_t)b * (size_t)cap;

    for (uint32_t k = (uint32_t)threadIdx.x * 4u; k < size; k += TPB_A * 4u) {
        if (k + 4u <= size) {
            uint4 r4 = *(const uint4*)(src + k);
            atomicAdd(&acc[r4.x >> 19], unpack_val(r4.x));
            atomicAdd(&acc[r4.y >> 19], unpack_val(r4.y));
            atomicAdd(&acc[r4.z >> 19], unpack_val(r4.z));
            atomicAdd(&acc[r4.w >> 19], unpack_val(r4.w));
        } else {
            for (uint32_t kk = k; kk < size; ++kk) {
                uint32_t r = src[kk];
                atomicAdd(&acc[r >> 19], unpack_val(r));
            }
        }
    }
    __syncthreads();

    int g0 = b << ABITS;
    for (int l = threadIdx.x; l < APB; l += TPB_A) {
        int g = g0 + l;
        if (g < N) out[g] = pae[g] + spill[g] + acc[l];
    }
}

// ---- Fallback path (ws too small): device-scope atomics ------------------
__global__ __launch_bounds__(256) void init_out_kernel(
    const float* __restrict__ pae, float* __restrict__ out, int N)
{
    int i = blockIdx.x * 256 + threadIdx.x;
    if (i < N) out[i] = pae[i];
}

__global__ __launch_bounds__(256) void edge_kernel_dev(
    const float* __restrict__ el, const int* __restrict__ ec,
    const int* __restrict__ en, const int* __restrict__ species,
    const float* __restrict__ scales, float* __restrict__ out, int E, int T)
{
    int i = blockIdx.x * 256 + threadIdx.x;
    if (i >= E) return;
    float r = el[i];
    int c = ec[i], n = en[i];
    float l0 = scales[species[c] * T + species[n]];
    float e = edge_energy(r, l0);
    if (e != 0.0f) atomicAdd(&out[c], e);
}

extern "C" void kernel_launch(void* const* d_in, const int* in_sizes, int n_in,
                              void* d_out, int out_size, void* d_ws, size_t ws_size,
                              hipStream_t stream) {
    const float* el      = (const float*)d_in[0];
    const int*   eidx    = (const int*)  d_in[1];   // (2,E): [0:E) center, [E:2E) neighbor
    const int*   species = (const int*)  d_in[2];
    const float* pae     = (const float*)d_in[3];
    const float* scales  = (const float*)d_in[4];
    float*       out     = (float*)d_out;

    const int E = in_sizes[0];
    const int N = in_sizes[3];
    int T = 1;
    while (T * T < in_sizes[4]) ++T;   // T = 5

    const int nb  = (N + APB - 1) / APB;           // 245 buckets
    const int nb1 = (E + EPB - 1) / EPB;           // 3907 scatter blocks
    // per-bucket capacity: ~1.25x mean, rounded up to 1024 (uint4-aligned)
    const int cap = (int)((((size_t)E / (size_t)nb) * 5 / 4 + 1023) & ~(size_t)1023);

    size_t off = 0;
    auto take = [&](size_t bytes) { size_t o = off; off += (bytes + 15) & ~(size_t)15; return o; };
    size_t o_bucketed = take((size_t)nb * (size_t)cap * 4);
    size_t o_cursors  = take((size_t)MAXB * 4);
    size_t o_spill    = take((size_t)N * 4);
    size_t o_uflag    = take(16);
    const size_t need = off;

    if (nb <= MAXB && ws_size >= need) {
        char* ws = (char*)d_ws;
        uint32_t* bucketed = (uint32_t*)(ws + o_bucketed);
        uint32_t* cursors  = (uint32_t*)(ws + o_cursors);
        float*    spill    = (float*)   (ws + o_spill);
        uint32_t* uflag    = (uint32_t*)(ws + o_uflag);

        hipMemsetAsync(cursors, 0, (size_t)MAXB * 4, stream);
        hipMemsetAsync(spill,   0, (size_t)N * 4, stream);

        k_check<<<1, 1, 0, stream>>>(scales, T * T, uflag);
        k_scatter<<<nb1, TPB_S, 0, stream>>>(el, eidx, eidx + E, species, scales,
                                             uflag, cursors, bucketed, spill,
                                             E, nb, T, cap);
        k_accum_out<<<nb, TPB_A, 0, stream>>>(bucketed, cursors, spill, pae, out, N, cap);
    } else {
        init_out_kernel<<<(N + 255) / 256, 256, 0, stream>>>(pae, out, N);
        edge_kernel_dev<<<(E + 255) / 256, 256, 0, stream>>>(
            el, eidx, eidx + E, species, scales, out, E, T);
    }
}